// Round 6
// baseline (241.595 us; speedup 1.0000x reference)
//
#include <hip/hip_runtime.h>
#include <math.h>

#define FILTERS 8
#define NB 32
#define NT 16
#define NH 64
#define NW 64
#define NC 3
#define GATES 32   // 4*FILTERS

// LDS tile: 11 planes (0-2: x channels, 3-10: h filters), 4 rows (2 output
// rows + halo), 66 cols (zero-padded halo). Planar -> conv reads are
// consecutive-lane ds_read_b32, conflict-free.
#define TROWS 4
#define TCOLS 66
#define LIDX(p, r, c) (((p) * TROWS + (r)) * TCOLS + (c))

__device__ __forceinline__ float hard_sigmoid(float v) {
    return fminf(fmaxf(fmaf(0.2f, v, 0.5f), 0.0f), 1.0f);
}

// tanh(x) = 1 - 2/(exp(2x)+1). Validated absmax 0.0 in rounds 2-5.
__device__ __forceinline__ float fast_tanh(float v) {
    float e = __builtin_amdgcn_exp2f(v * 2.8853900817779268f);
    return 1.0f - 2.0f * __builtin_amdgcn_rcpf(e + 1.0f);
}

// Block = 256 threads: {filter-half (2)} x {2 rows} x {64 cols}.
// Grid = 32 batches x 32 row-groups = 1024 blocks.
// 11.6 KB LDS + 64 VGPR -> target 8 blocks/CU = 32 waves/CU for latency hiding.
__global__ __launch_bounds__(256, 8) void convlstm_step(
    const float* __restrict__ x,     // (B,T,H,W,C)
    const float* __restrict__ Wx,    // (3,3,3,32)
    const float* __restrict__ Wh,    // (3,3,8,32)
    const float* __restrict__ bias,  // (32,)
    const float* __restrict__ h_in,  // (B,H,W,8)
    float* __restrict__ h_out,       // (B,H,W,8)
    float* __restrict__ c_buf,       // (B,H,W,8)
    int t, int first)
{
    __shared__ float lds[11 * TROWS * TCOLS];

    const int bi  = blockIdx.x >> 5;          // batch
    const int r0  = (blockIdx.x & 31) << 1;   // first output row
    const int tid = threadIdx.x;
    // Wave-uniform (128-thread boundary = 2 waves). readfirstlane pins to SGPR
    // so all weight addresses stay scalar (s_load), not per-lane VMEM.
    const int half = __builtin_amdgcn_readfirstlane(tid >> 7);
    const int idx  = tid & 127;
    const int yloc = idx >> 6;                // 0..1
    const int xloc = idx & 63;

    const float* xt = x + (((size_t)bi * NT + t) * NH * NW) * NC;

    // ---- cooperative staging: x tile (3 planes) + h tile (8 planes) ----
    for (int i = tid; i < TROWS * TCOLS; i += 256) {
        int row_l = i / TCOLS;
        int col_l = i - row_l * TCOLS;
        int yg = r0 - 1 + row_l;
        int xg = col_l - 1;
        float xv0 = 0.f, xv1 = 0.f, xv2 = 0.f;
        float hv0 = 0.f, hv1 = 0.f, hv2 = 0.f, hv3 = 0.f;
        float hv4 = 0.f, hv5 = 0.f, hv6 = 0.f, hv7 = 0.f;
        if ((unsigned)yg < NH && (unsigned)xg < NW) {
            const float* xp = xt + (yg * NW + xg) * NC;
            xv0 = xp[0]; xv1 = xp[1]; xv2 = xp[2];
            if (!first) {
                const float* hp = h_in + (((size_t)bi * NH + yg) * NW + xg) * FILTERS;
                float4 a  = *(const float4*)hp;
                float4 b4 = *(const float4*)(hp + 4);
                hv0 = a.x;  hv1 = a.y;  hv2 = a.z;  hv3 = a.w;
                hv4 = b4.x; hv5 = b4.y; hv6 = b4.z; hv7 = b4.w;
            }
        }
        lds[LIDX(0, row_l, col_l)]  = xv0;
        lds[LIDX(1, row_l, col_l)]  = xv1;
        lds[LIDX(2, row_l, col_l)]  = xv2;
        lds[LIDX(3, row_l, col_l)]  = hv0;
        lds[LIDX(4, row_l, col_l)]  = hv1;
        lds[LIDX(5, row_l, col_l)]  = hv2;
        lds[LIDX(6, row_l, col_l)]  = hv3;
        lds[LIDX(7, row_l, col_l)]  = hv4;
        lds[LIDX(8, row_l, col_l)]  = hv5;
        lds[LIDX(9, row_l, col_l)]  = hv6;
        lds[LIDX(10, row_l, col_l)] = hv7;
    }

    // Issue the c-state load BEFORE the barrier: independent of LDS, its
    // latency overlaps the conv compute below.
    const int gpix = (bi << 12) | ((r0 + yloc) << 6) | xloc;
    const size_t off = (size_t)gpix * FILTERS + half * 4;
    float c_old[4] = {0.f, 0.f, 0.f, 0.f};
    if (!first) {
        float4 cv = *(const float4*)(c_buf + off);
        c_old[0] = cv.x; c_old[1] = cv.y; c_old[2] = cv.z; c_old[3] = cv.w;
    }

    __syncthreads();

    // ---- conv: 16 gate channels (4 filters x 4 gates) for this half ----
    float z[16];
    #pragma unroll
    for (int g = 0; g < 4; ++g)
        #pragma unroll
        for (int fi = 0; fi < 4; ++fi)
            z[g * 4 + fi] = bias[g * 8 + half * 4 + fi];

    #pragma unroll
    for (int ky = 0; ky < 3; ++ky) {
        #pragma unroll
        for (int kx = 0; kx < 3; ++kx) {
            const int rr = yloc + ky;   // 0..3
            const int cc = xloc + kx;   // 0..65

            float xa  = lds[LIDX(0, rr, cc)];
            float xb  = lds[LIDX(1, rr, cc)];
            float xc2 = lds[LIDX(2, rr, cc)];
            const float* wxp = Wx + ((ky * 3 + kx) * NC) * GATES + half * 4;
            #pragma unroll
            for (int g = 0; g < 4; ++g)
                #pragma unroll
                for (int fi = 0; fi < 4; ++fi) {
                    int co = g * 8 + fi;
                    float acc = z[g * 4 + fi];
                    acc = fmaf(xa,  wxp[co], acc);
                    acc = fmaf(xb,  wxp[GATES + co], acc);
                    acc = fmaf(xc2, wxp[2 * GATES + co], acc);
                    z[g * 4 + fi] = acc;
                }

            if (!first) {
                float hv[FILTERS];
                #pragma unroll
                for (int ci = 0; ci < FILTERS; ++ci)
                    hv[ci] = lds[LIDX(3 + ci, rr, cc)];
                const float* whp = Wh + ((ky * 3 + kx) * FILTERS) * GATES + half * 4;
                #pragma unroll
                for (int ci = 0; ci < FILTERS; ++ci)
                    #pragma unroll
                    for (int g = 0; g < 4; ++g)
                        #pragma unroll
                        for (int fi = 0; fi < 4; ++fi)
                            z[g * 4 + fi] = fmaf(hv[ci], whp[ci * GATES + g * 8 + fi],
                                                 z[g * 4 + fi]);
            }
        }
    }

    // ---- gates + state update (4 filters of this half) ----
    float hn[4], cn[4];
    #pragma unroll
    for (int fi = 0; fi < 4; ++fi) {
        float ig = hard_sigmoid(z[0 * 4 + fi]);
        float fg = hard_sigmoid(z[1 * 4 + fi]);
        float gg = fast_tanh(z[2 * 4 + fi]);
        float og = hard_sigmoid(z[3 * 4 + fi]);
        float cc = fmaf(fg, c_old[fi], ig * gg);
        cn[fi] = cc;
        hn[fi] = og * fast_tanh(cc);
    }

    *(float4*)(c_buf + off) = make_float4(cn[0], cn[1], cn[2], cn[3]);
    *(float4*)(h_out + off) = make_float4(hn[0], hn[1], hn[2], hn[3]);
}

// Stage 1: 512 blocks (32 batches x 16 chunks); each reduces 2048 elements.
__global__ __launch_bounds__(256) void head_partial(
    const float* __restrict__ h,     // (B, 32768)
    const float* __restrict__ Wout,  // (32768, 4)
    float* __restrict__ partial)     // (B*16, 4)
{
    const int b = blockIdx.x >> 4;
    const int chunk = blockIdx.x & 15;
    const int tid = threadIdx.x;
    const float* hb = h + (size_t)b * 32768 + chunk * 2048;
    const float* wb = Wout + (size_t)(chunk * 2048) * 4;

    float acc[4] = {0.f, 0.f, 0.f, 0.f};
    #pragma unroll
    for (int it = 0; it < 8; ++it) {
        int i = it * 256 + tid;
        float hv = hb[i];
        float4 w = *(const float4*)(wb + (size_t)i * 4);
        acc[0] = fmaf(hv, w.x, acc[0]);
        acc[1] = fmaf(hv, w.y, acc[1]);
        acc[2] = fmaf(hv, w.z, acc[2]);
        acc[3] = fmaf(hv, w.w, acc[3]);
    }

    #pragma unroll
    for (int j = 0; j < 4; ++j)
        #pragma unroll
        for (int off = 32; off >= 1; off >>= 1)
            acc[j] += __shfl_down(acc[j], off, 64);

    __shared__ float red[4][4];
    int lane = tid & 63, wv = tid >> 6;
    if (lane == 0) {
        #pragma unroll
        for (int j = 0; j < 4; ++j) red[wv][j] = acc[j];
    }
    __syncthreads();
    if (tid == 0) {
        #pragma unroll
        for (int j = 0; j < 4; ++j)
            partial[(size_t)blockIdx.x * 4 + j] =
                red[0][j] + red[1][j] + red[2][j] + red[3][j];
    }
}

__global__ __launch_bounds__(64) void head_finish(
    const float* __restrict__ partial,  // (B*16, 4)
    const float* __restrict__ bout,     // (4,)
    float* __restrict__ out)            // (B, 4)
{
    int b = threadIdx.x;
    if (b >= NB) return;
    float logit[4] = {bout[0], bout[1], bout[2], bout[3]};
    #pragma unroll
    for (int k = 0; k < 16; ++k) {
        const float* p = partial + (size_t)(b * 16 + k) * 4;
        logit[0] += p[0]; logit[1] += p[1]; logit[2] += p[2]; logit[3] += p[3];
    }
    float m = fmaxf(fmaxf(logit[0], logit[1]), fmaxf(logit[2], logit[3]));
    float e[4], s = 0.f;
    #pragma unroll
    for (int j = 0; j < 4; ++j) { e[j] = expf(logit[j] - m); s += e[j]; }
    float inv = 1.0f / s;
    #pragma unroll
    for (int j = 0; j < 4; ++j) out[b * 4 + j] = e[j] * inv;
}

extern "C" void kernel_launch(void* const* d_in, const int* in_sizes, int n_in,
                              void* d_out, int out_size, void* d_ws, size_t ws_size,
                              hipStream_t stream) {
    const float* x    = (const float*)d_in[0];
    const float* Wx   = (const float*)d_in[1];
    const float* Wh   = (const float*)d_in[2];
    const float* b    = (const float*)d_in[3];
    const float* Wout = (const float*)d_in[4];
    const float* bout = (const float*)d_in[5];
    float* out = (float*)d_out;

    const size_t state_elems = (size_t)NB * NH * NW * FILTERS;  // 1,048,576
    float* h0 = (float*)d_ws;
    float* h1 = h0 + state_elems;
    float* cb = h1 + state_elems;
    float* partial = cb + state_elems;   // 512*4 floats

    dim3 block(256);
    dim3 grid(NB * 32);   // 1024 blocks: (batch, row-group)

    for (int t = 0; t < NT; ++t) {
        const float* hin = (t & 1) ? h0 : h1;   // t=0 ignores hin (first=1)
        float* hout      = (t & 1) ? h1 : h0;
        convlstm_step<<<grid, block, 0, stream>>>(x, Wx, Wh, b, hin, hout, cb,
                                                  t, (t == 0) ? 1 : 0);
    }
    // t = 15 wrote h1
    head_partial<<<512, 256, 0, stream>>>(h1, Wout, partial);
    head_finish<<<1, 64, 0, stream>>>(partial, bout, out);
}

// Round 7
// 110.690 us; speedup vs baseline: 2.1826x; 2.1826x over previous
//
#include <hip/hip_runtime.h>
#include <math.h>

#define FILTERS 8
#define NB 32
#define NT 16
#define NH 64
#define NW 64

typedef _Float16 f16;
typedef _Float16 half2f __attribute__((ext_vector_type(2)));
typedef _Float16 half4f __attribute__((ext_vector_type(4)));
typedef _Float16 half8f __attribute__((ext_vector_type(8)));
typedef float    floatx2 __attribute__((ext_vector_type(2)));
typedef float    floatx4 __attribute__((ext_vector_type(4)));

// LDS layout (bytes), per 2-row x 64-col block:
//   H tile : 4 rows x 68 cols x 8ch f16  = 4352 B   (row-halo 1, col-halo 1+3)
//   X tile : 4 rows x 68 cols x 4ch f16  = 2176 B   (ch3 zero-padded)
//   ZBUF   : 4 waves x 16px x 33 x f32   = 8448 B   (C->gate transpose)
#define XOFF 4352
#define ZOFF 6528
#define SMEM_BYTES 14976

__device__ __forceinline__ float hard_sigmoid(float v) {
    return fminf(fmaxf(fmaf(0.2f, v, 0.5f), 0.0f), 1.0f);
}
__device__ __forceinline__ float fast_tanh(float v) {
    float e = __builtin_amdgcn_exp2f(v * 2.8853900817779268f);
    return 1.0f - 2.0f * __builtin_amdgcn_rcpf(e + 1.0f);
}

// ---- B-fragment prepack: WB[j][n][lane][e], j=K-group(4), n=gate-half(2) ----
// Logical k mapping (must mirror the step kernel's A reads):
//  j0: h tap g4        (ci = e)
//  j1: h tap 4+g4      (ci = e)
//  j2: g4==0: h tap 8; g4=1:(x ty0,txp0) g4=2:(x ty0,txp2) g4=3:(x ty1,txp0)
//  j3: g4=0:(x ty1,txp2) g4=1:(x ty2,txp0) g4=2:(x ty2,txp2) g4=3: ZERO (dup A)
//  x element: txq = txp + (e>>2), c = e&3; weight 0 if txq==3 or c==3.
__global__ __launch_bounds__(256) void prepack(
    const float* __restrict__ Wx,   // (3,3,3,32)
    const float* __restrict__ Wh,   // (3,3,8,32)
    f16* __restrict__ WB)           // 4096 entries
{
    int i = blockIdx.x * 256 + threadIdx.x;
    if (i >= 4096) return;
    int e = i & 7;
    int l = (i >> 3) & 63;
    int n = (i >> 9) & 1;
    int j = i >> 10;
    int h = l >> 4;
    int g = n * 16 + (l & 15);

    float wv = 0.f;
    if (j == 0) {
        wv = Wh[(h * 8 + e) * 32 + g];
    } else if (j == 1) {
        wv = Wh[((4 + h) * 8 + e) * 32 + g];
    } else if (j == 2 && h == 0) {
        wv = Wh[(8 * 8 + e) * 32 + g];
    } else if (!(j == 3 && h == 3)) {
        int ty, txp;
        if (j == 2) { ty = (h == 3) ? 1 : 0; txp = (h == 2) ? 2 : 0; }
        else        { ty = (h == 0) ? 1 : 2; txp = (h == 1) ? 0 : 2; }
        int txq = txp + (e >> 2);
        int c = e & 3;
        if (txq < 3 && c < 3)
            wv = Wx[((ty * 3 + txq) * 3 + c) * 32 + g];
    }
    WB[i] = (f16)wv;
}

#define LDA(off) ({                                                        \
    half4f lo_ = *(const half4f*)(smem + (off));                           \
    half4f hi_ = *(const half4f*)(smem + (off) + 8);                       \
    __builtin_shufflevector(lo_, hi_, 0, 1, 2, 3, 4, 5, 6, 7); })

// Block = 256 threads (4 waves): 2 output rows x 64 cols of one batch.
// Wave w: row = w>>1, col-tiles c0 = (w&1)*32 + tt*16, tt=0,1.
// Grid = 32 batches x 32 row-groups = 1024 blocks -> 4 blocks/CU.
__global__ __launch_bounds__(256, 4) void convlstm_step(
    const float* __restrict__ x,     // (B,T,H,W,3) f32
    const f16*   __restrict__ WB,    // prepacked B fragments
    const float* __restrict__ bias,  // (32,)
    const f16*   __restrict__ h_in,  // (B,H,W,8) f16
    f16*         __restrict__ h_out, // (B,H,W,8) f16
    float*       __restrict__ c_buf, // (B,H,W,8) f32
    int t, int first)
{
    __shared__ __attribute__((aligned(16))) char smem[SMEM_BYTES];

    const int bid = blockIdx.x;
    const int bi  = bid >> 5;
    const int r0  = (bid & 31) << 1;
    const int tid = threadIdx.x;
    const int w    = tid >> 6;
    const int lane = tid & 63;
    const int p16  = lane & 15;
    const int g4   = lane >> 4;
    const int pr   = w >> 1;            // 0..1
    const int wcol = (w & 1) << 5;      // 0 or 32

    const float* xt = x + (((size_t)bi * NT + t) * 4096) * 3;

    // ---- staging: 4 rows x 68 cols, zero-padded halo ----
    for (int i = tid; i < 272; i += 256) {
        int lr = i / 68;
        int lc = i - lr * 68;
        int gr = r0 - 1 + lr;
        int gc = lc - 1;
        bool ok = ((unsigned)gr < 64u) && ((unsigned)gc < 64u);
        half4f xv = {0, 0, 0, 0};
        half8f hv = {0, 0, 0, 0, 0, 0, 0, 0};
        if (ok) {
            const float* xp = xt + (gr * 64 + gc) * 3;
            xv[0] = (f16)xp[0]; xv[1] = (f16)xp[1]; xv[2] = (f16)xp[2];
            if (!first)
                hv = *(const half8f*)(h_in + ((size_t)(bi * 4096 + gr * 64 + gc)) * 8);
        }
        *(half8f*)(smem + (lr * 68 + lc) * 16) = hv;
        *(half4f*)(smem + XOFF + (lr * 68 + lc) * 8) = xv;
    }

    // ---- B fragments + bias (wave-invariant across tiles) ----
    const half8f* WBv = (const half8f*)WB;
    half8f B00 = WBv[0 * 64 + lane], B01 = WBv[1 * 64 + lane];
    half8f B10 = WBv[2 * 64 + lane], B11 = WBv[3 * 64 + lane];
    half8f B20 = WBv[4 * 64 + lane], B21 = WBv[5 * 64 + lane];
    half8f B30 = WBv[6 * 64 + lane], B31 = WBv[7 * 64 + lane];
    const float bz0 = bias[p16];
    const float bz1 = bias[16 + p16];

    __syncthreads();

    // ---- per-lane A-fragment LDS byte offsets (tile tt=0) ----
    // j0: h taps 0..3 ; j1: h taps 4..7 (tap = ty*3+tx)
    const int ty0 = (g4 >= 3) ? 1 : 0, tx0 = g4 - 3 * ty0;
    const int ty1 = 1 + ((g4 >= 2) ? 1 : 0), tx1 = (g4 + 4) - 3 * ty1;
    int o0 = ((pr + ty0) * 68 + wcol + p16 + tx0) * 16;
    int o1 = ((pr + ty1) * 68 + wcol + p16 + tx1) * 16;
    const int o2h = ((pr + 2) * 68 + wcol + p16 + 2) * 16;          // h tap 8
    const int ty2 = (g4 == 3) ? 1 : 0, tx2 = (g4 == 2) ? 2 : 0;
    const int o2x = XOFF + ((pr + ty2) * 68 + wcol + p16 + tx2) * 8;
    int o2 = (g4 == 0) ? o2h : o2x;
    const int inc2 = (g4 == 0) ? 256 : 128;
    const int ty3 = (g4 == 0) ? 1 : 2, tx3 = (g4 == 1) ? 0 : 2;
    int o3 = XOFF + ((pr + ty3) * 68 + wcol + p16 + tx3) * 8;

    const int zb = ZOFF + w * 2112;
    const int f0 = g4 * 2;

    #pragma unroll
    for (int tt = 0; tt < 2; ++tt) {
        half8f a0 = LDA(o0);
        half8f a1 = LDA(o1);
        half8f a2 = LDA(o2);
        half8f a3 = LDA(o3);

        floatx4 acc0 = {bz0, bz0, bz0, bz0};
        floatx4 acc1 = {bz1, bz1, bz1, bz1};
        acc0 = __builtin_amdgcn_mfma_f32_16x16x32_f16(a0, B00, acc0, 0, 0, 0);
        acc1 = __builtin_amdgcn_mfma_f32_16x16x32_f16(a0, B01, acc1, 0, 0, 0);
        acc0 = __builtin_amdgcn_mfma_f32_16x16x32_f16(a1, B10, acc0, 0, 0, 0);
        acc1 = __builtin_amdgcn_mfma_f32_16x16x32_f16(a1, B11, acc1, 0, 0, 0);
        acc0 = __builtin_amdgcn_mfma_f32_16x16x32_f16(a2, B20, acc0, 0, 0, 0);
        acc1 = __builtin_amdgcn_mfma_f32_16x16x32_f16(a2, B21, acc1, 0, 0, 0);
        acc0 = __builtin_amdgcn_mfma_f32_16x16x32_f16(a3, B30, acc0, 0, 0, 0);
        acc1 = __builtin_amdgcn_mfma_f32_16x16x32_f16(a3, B31, acc1, 0, 0, 0);

        // ---- transpose C (col=gate lane&15, row=pixel g4*4+r) via wave-local LDS ----
        #pragma unroll
        for (int r = 0; r < 4; ++r) {
            *(float*)(smem + zb + ((g4 * 4 + r) * 33 + p16) * 4)      = acc0[r];
            *(float*)(smem + zb + ((g4 * 4 + r) * 33 + 16 + p16) * 4) = acc1[r];
        }
        asm volatile("s_waitcnt lgkmcnt(0)" ::: "memory");

        // lane -> pixel p16, filters f0, f0+1
        float zi0 = *(const float*)(smem + zb + (p16 * 33 + f0) * 4);
        float zi1 = *(const float*)(smem + zb + (p16 * 33 + f0 + 1) * 4);
        float zf0 = *(const float*)(smem + zb + (p16 * 33 + 8 + f0) * 4);
        float zf1 = *(const float*)(smem + zb + (p16 * 33 + 8 + f0 + 1) * 4);
        float zc0 = *(const float*)(smem + zb + (p16 * 33 + 16 + f0) * 4);
        float zc1 = *(const float*)(smem + zb + (p16 * 33 + 16 + f0 + 1) * 4);
        float zo0 = *(const float*)(smem + zb + (p16 * 33 + 24 + f0) * 4);
        float zo1 = *(const float*)(smem + zb + (p16 * 33 + 24 + f0 + 1) * 4);

        const int gcol = wcol + tt * 16 + p16;
        const size_t gpix = (size_t)(bi * 4096 + (r0 + pr) * 64 + gcol);

        floatx2 cold = {0.f, 0.f};
        if (!first) cold = *(const floatx2*)(c_buf + gpix * 8 + f0);

        float ig0 = hard_sigmoid(zi0), fg0 = hard_sigmoid(zf0);
        float cg0 = fast_tanh(zc0),    og0 = hard_sigmoid(zo0);
        float cc0 = fmaf(fg0, cold[0], ig0 * cg0);
        float hh0 = og0 * fast_tanh(cc0);
        float ig1 = hard_sigmoid(zi1), fg1 = hard_sigmoid(zf1);
        float cg1 = fast_tanh(zc1),    og1 = hard_sigmoid(zo1);
        float cc1 = fmaf(fg1, cold[1], ig1 * cg1);
        float hh1 = og1 * fast_tanh(cc1);

        floatx2 cw2 = {cc0, cc1};
        *(floatx2*)(c_buf + gpix * 8 + f0) = cw2;
        half2f hw = {(f16)hh0, (f16)hh1};
        *(half2f*)(h_out + gpix * 8 + f0) = hw;

        o0 += 256; o1 += 256; o2 += inc2; o3 += 128;
    }
}

// Stage 1: 512 blocks (32 batches x 16 chunks); each reduces 2048 elements.
__global__ __launch_bounds__(256) void head_partial(
    const f16* __restrict__ h,       // (B, 32768) f16
    const float* __restrict__ Wout,  // (32768, 4)
    float* __restrict__ partial)     // (B*16, 4)
{
    const int b = blockIdx.x >> 4;
    const int chunk = blockIdx.x & 15;
    const int tid = threadIdx.x;
    const f16* hb = h + (size_t)b * 32768 + chunk * 2048;
    const float* wb = Wout + (size_t)(chunk * 2048) * 4;

    float acc[4] = {0.f, 0.f, 0.f, 0.f};
    #pragma unroll
    for (int it = 0; it < 8; ++it) {
        int i = it * 256 + tid;
        float hv = (float)hb[i];
        float4 wv = *(const float4*)(wb + (size_t)i * 4);
        acc[0] = fmaf(hv, wv.x, acc[0]);
        acc[1] = fmaf(hv, wv.y, acc[1]);
        acc[2] = fmaf(hv, wv.z, acc[2]);
        acc[3] = fmaf(hv, wv.w, acc[3]);
    }
    #pragma unroll
    for (int j = 0; j < 4; ++j)
        #pragma unroll
        for (int off = 32; off >= 1; off >>= 1)
            acc[j] += __shfl_down(acc[j], off, 64);

    __shared__ float red[4][4];
    int lane = tid & 63, wv2 = tid >> 6;
    if (lane == 0) {
        #pragma unroll
        for (int j = 0; j < 4; ++j) red[wv2][j] = acc[j];
    }
    __syncthreads();
    if (tid == 0) {
        #pragma unroll
        for (int j = 0; j < 4; ++j)
            partial[(size_t)blockIdx.x * 4 + j] =
                red[0][j] + red[1][j] + red[2][j] + red[3][j];
    }
}

__global__ __launch_bounds__(64) void head_finish(
    const float* __restrict__ partial,  // (B*16, 4)
    const float* __restrict__ bout,     // (4,)
    float* __restrict__ out)            // (B, 4)
{
    int b = threadIdx.x;
    if (b >= NB) return;
    float logit[4] = {bout[0], bout[1], bout[2], bout[3]};
    #pragma unroll
    for (int k = 0; k < 16; ++k) {
        const float* p = partial + (size_t)(b * 16 + k) * 4;
        logit[0] += p[0]; logit[1] += p[1]; logit[2] += p[2]; logit[3] += p[3];
    }
    float m = fmaxf(fmaxf(logit[0], logit[1]), fmaxf(logit[2], logit[3]));
    float e[4], s = 0.f;
    #pragma unroll
    for (int j = 0; j < 4; ++j) { e[j] = expf(logit[j] - m); s += e[j]; }
    float inv = 1.0f / s;
    #pragma unroll
    for (int j = 0; j < 4; ++j) out[b * 4 + j] = e[j] * inv;
}

extern "C" void kernel_launch(void* const* d_in, const int* in_sizes, int n_in,
                              void* d_out, int out_size, void* d_ws, size_t ws_size,
                              hipStream_t stream) {
    const float* x    = (const float*)d_in[0];
    const float* Wx   = (const float*)d_in[1];
    const float* Wh   = (const float*)d_in[2];
    const float* b    = (const float*)d_in[3];
    const float* Wout = (const float*)d_in[4];
    const float* bout = (const float*)d_in[5];
    float* out = (float*)d_out;

    char* ws = (char*)d_ws;
    f16*   h0      = (f16*)ws;                       // 2 MB
    f16*   h1      = (f16*)(ws + (1u << 21));        // 2 MB
    float* cb      = (float*)(ws + (1u << 22));      // 4 MB
    f16*   WB      = (f16*)(ws + (1u << 23));        // 8 KB
    float* partial = (float*)(ws + (1u << 23) + 8192);

    prepack<<<16, 256, 0, stream>>>(Wx, Wh, WB);

    for (int t = 0; t < NT; ++t) {
        const f16* hin = (t & 1) ? h0 : h1;   // t=0 ignores hin (first=1)
        f16* hout      = (t & 1) ? h1 : h0;
        convlstm_step<<<1024, 256, 0, stream>>>(x, WB, b, hin, hout, cb,
                                                t, (t == 0) ? 1 : 0);
    }
    // t = 15 wrote h1
    head_partial<<<512, 256, 0, stream>>>(h1, Wout, partial);
    head_finish<<<1, 64, 0, stream>>>(partial, bout, out);
}

// Round 8
// 109.178 us; speedup vs baseline: 2.2128x; 1.0138x over previous
//
#include <hip/hip_runtime.h>
#include <math.h>

#define FILTERS 8
#define NB 32
#define NT 16
#define NH 64
#define NW 64

typedef _Float16 f16;
typedef _Float16 half2f __attribute__((ext_vector_type(2)));
typedef _Float16 half4f __attribute__((ext_vector_type(4)));
typedef _Float16 half8f __attribute__((ext_vector_type(8)));
typedef float    floatx2 __attribute__((ext_vector_type(2)));
typedef float    floatx4 __attribute__((ext_vector_type(4)));

// LDS layout (bytes), per 2-row x 64-col block:
//   H tile : 4 rows x 68 cols x 8ch f16  = 4352 B   (row-halo 1, col-halo 1+3)
//   X tile : 4 rows x 68 cols x 4ch f16  = 2176 B   (ch3 == 1.0: bias slot)
#define XOFF 4352
#define SMEM_BYTES 6528

__device__ __forceinline__ float hard_sigmoid(float v) {
    return fminf(fmaxf(fmaf(0.2f, v, 0.5f), 0.0f), 1.0f);
}
__device__ __forceinline__ float fast_tanh(float v) {
    float e = __builtin_amdgcn_exp2f(v * 2.8853900817779268f);
    return 1.0f - 2.0f * __builtin_amdgcn_rcpf(e + 1.0f);
}

// ---- Weight-fragment prepack: WB[j][n][lane][e], j=K-group(4), n=gate-half(2)
// Weights are the MFMA *A* operand (M=gates), patch is B (N=pixels); both use
// the same (lane,e)->k map (validated empirically in round 7).
// Logical k mapping (mirrors the step kernel's patch reads):
//  j0: h tap g4        (ci = e)
//  j1: h tap 4+g4      (ci = e)
//  j2: g4==0: h tap 8; g4=1:(x ty0,txp0) g4=2:(x ty0,txp2) g4=3:(x ty1,txp0)
//  j3: g4=0:(x ty1,txp2) g4=1:(x ty2,txp0) g4=2:(x ty2,txp2)
//      g4=3: e==3 -> BIAS (patch ch3 == 1.0), else zero (dup patch read)
//  x element: txq = txp + (e>>2), c = e&3; weight 0 if txq==3 or c==3.
__global__ __launch_bounds__(256) void prepack(
    const float* __restrict__ Wx,    // (3,3,3,32)
    const float* __restrict__ Wh,    // (3,3,8,32)
    const float* __restrict__ bias,  // (32,)
    f16* __restrict__ WB)            // 4096 entries
{
    int i = blockIdx.x * 256 + threadIdx.x;
    if (i >= 4096) return;
    int e = i & 7;
    int l = (i >> 3) & 63;
    int n = (i >> 9) & 1;
    int j = i >> 10;
    int h = l >> 4;
    int g = n * 16 + (l & 15);

    float wv = 0.f;
    if (j == 0) {
        wv = Wh[(h * 8 + e) * 32 + g];
    } else if (j == 1) {
        wv = Wh[((4 + h) * 8 + e) * 32 + g];
    } else if (j == 2 && h == 0) {
        wv = Wh[(8 * 8 + e) * 32 + g];
    } else if (j == 3 && h == 3) {
        wv = (e == 3) ? bias[g] : 0.f;   // bias rides the const-1.0 patch slot
    } else {
        int ty, txp;
        if (j == 2) { ty = (h == 3) ? 1 : 0; txp = (h == 2) ? 2 : 0; }
        else        { ty = (h == 0) ? 1 : 2; txp = (h == 1) ? 0 : 2; }
        int txq = txp + (e >> 2);
        int c = e & 3;
        if (txq < 3 && c < 3)
            wv = Wx[((ty * 3 + txq) * 3 + c) * 32 + g];
    }
    WB[i] = (f16)wv;
}

#define LDA(off) ({                                                        \
    half4f lo_ = *(const half4f*)(smem + (off));                           \
    half4f hi_ = *(const half4f*)(smem + (off) + 8);                       \
    __builtin_shufflevector(lo_, hi_, 0, 1, 2, 3, 4, 5, 6, 7); })

// Block = 256 threads (4 waves): 2 output rows x 64 cols of one batch.
// Wave w: row = w>>1, col-tiles (w&1)*32 + tt*16, tt=0,1.
// Grid = 32 batches x 32 row-groups = 1024 blocks -> 4 blocks/CU.
__global__ __launch_bounds__(256, 4) void convlstm_step(
    const float* __restrict__ x,     // (B,T,H,W,3) f32
    const f16*   __restrict__ WB,    // prepacked A fragments (weights+bias)
    const f16*   __restrict__ h_in,  // (B,H,W,8) f16
    f16*         __restrict__ h_out, // (B,H,W,8) f16
    float*       __restrict__ c_buf, // (B,H,W,8) f32
    int t, int first)
{
    __shared__ __attribute__((aligned(16))) char smem[SMEM_BYTES];

    const int bid = blockIdx.x;
    const int bi  = bid >> 5;
    const int r0  = (bid & 31) << 1;
    const int tid = threadIdx.x;
    const int w    = tid >> 6;
    const int lane = tid & 63;
    const int p16  = lane & 15;
    const int g4   = lane >> 4;
    const int pr   = w >> 1;            // 0..1
    const int wcol = (w & 1) << 5;      // 0 or 32

    const float* xt = x + (((size_t)bi * NT + t) * 4096) * 3;

    // ---- staging: 4 rows x 68 cols, zero-padded halo; x ch3 == 1.0 ----
    for (int i = tid; i < 272; i += 256) {
        int lr = i / 68;
        int lc = i - lr * 68;
        int gr = r0 - 1 + lr;
        int gc = lc - 1;
        bool ok = ((unsigned)gr < 64u) && ((unsigned)gc < 64u);
        half4f xv = {0, 0, 0, (f16)1.0f};   // ch3: constant-1 bias feed
        half8f hv = {0, 0, 0, 0, 0, 0, 0, 0};
        if (ok) {
            const float* xp = xt + (gr * 64 + gc) * 3;
            xv[0] = (f16)xp[0]; xv[1] = (f16)xp[1]; xv[2] = (f16)xp[2];
            if (!first)
                hv = *(const half8f*)(h_in + ((size_t)(bi * 4096 + gr * 64 + gc)) * 8);
        }
        *(half8f*)(smem + (lr * 68 + lc) * 16) = hv;
        *(half4f*)(smem + XOFF + (lr * 68 + lc) * 8) = xv;
    }

    // ---- A fragments (weights, wave-invariant) ----
    const half8f* WBv = (const half8f*)WB;
    half8f B00 = WBv[0 * 64 + lane], B01 = WBv[1 * 64 + lane];
    half8f B10 = WBv[2 * 64 + lane], B11 = WBv[3 * 64 + lane];
    half8f B20 = WBv[4 * 64 + lane], B21 = WBv[5 * 64 + lane];
    half8f B30 = WBv[6 * 64 + lane], B31 = WBv[7 * 64 + lane];

    // ---- prefetch c-state for both tiles (independent of LDS / barrier) ----
    const int f0 = (g4 & 1) * 4 + (g4 & 2);   // 2 filters owned post-exchange
    const size_t rowbase = (size_t)(bi * 4096 + (r0 + pr) * 64);
    const size_t gp0 = rowbase + wcol + p16;
    const size_t gp1 = gp0 + 16;
    floatx2 cold0 = {0.f, 0.f}, cold1 = {0.f, 0.f};
    if (!first) {
        cold0 = *(const floatx2*)(c_buf + gp0 * 8 + f0);
        cold1 = *(const floatx2*)(c_buf + gp1 * 8 + f0);
    }

    __syncthreads();

    // ---- per-lane patch (B-operand) LDS byte offsets (tile tt=0) ----
    const int ty0 = (g4 >= 3) ? 1 : 0, tx0 = g4 - 3 * ty0;
    const int ty1 = 1 + ((g4 >= 2) ? 1 : 0), tx1 = (g4 + 4) - 3 * ty1;
    int o0 = ((pr + ty0) * 68 + wcol + p16 + tx0) * 16;
    int o1 = ((pr + ty1) * 68 + wcol + p16 + tx1) * 16;
    const int o2h = ((pr + 2) * 68 + wcol + p16 + 2) * 16;          // h tap 8
    const int ty2 = (g4 == 3) ? 1 : 0, tx2 = (g4 == 2) ? 2 : 0;
    const int o2x = XOFF + ((pr + ty2) * 68 + wcol + p16 + tx2) * 8;
    int o2 = (g4 == 0) ? o2h : o2x;
    const int inc2 = (g4 == 0) ? 256 : 128;
    const int ty3 = (g4 == 0) ? 1 : 2, tx3 = (g4 == 1) ? 0 : 2;
    int o3 = XOFF + ((pr + ty3) * 68 + wcol + p16 + tx3) * 8;

    #pragma unroll
    for (int tt = 0; tt < 2; ++tt) {
        half8f a0 = LDA(o0);
        half8f a1 = LDA(o1);
        half8f a2 = LDA(o2);
        half8f a3 = LDA(o3);

        floatx4 acc0 = {0.f, 0.f, 0.f, 0.f};   // gates 0-15  (rows of D)
        floatx4 acc1 = {0.f, 0.f, 0.f, 0.f};   // gates 16-31
        acc0 = __builtin_amdgcn_mfma_f32_16x16x32_f16(B00, a0, acc0, 0, 0, 0);
        acc1 = __builtin_amdgcn_mfma_f32_16x16x32_f16(B01, a0, acc1, 0, 0, 0);
        acc0 = __builtin_amdgcn_mfma_f32_16x16x32_f16(B10, a1, acc0, 0, 0, 0);
        acc1 = __builtin_amdgcn_mfma_f32_16x16x32_f16(B11, a1, acc1, 0, 0, 0);
        acc0 = __builtin_amdgcn_mfma_f32_16x16x32_f16(B20, a2, acc0, 0, 0, 0);
        acc1 = __builtin_amdgcn_mfma_f32_16x16x32_f16(B21, a2, acc1, 0, 0, 0);
        acc0 = __builtin_amdgcn_mfma_f32_16x16x32_f16(B30, a3, acc0, 0, 0, 0);
        acc1 = __builtin_amdgcn_mfma_f32_16x16x32_f16(B31, a3, acc1, 0, 0, 0);

        // D[row=gate g4*4+r (+16 for acc1)][col=pixel p16].
        // g4<2 holds i/c gates, g4>=2 holds f/o -> one 4-value exchange with
        // partner lane (g4^2) = lane^32 gives each lane i,f,c,o for 2 filters.
        float ex0 = (g4 & 2) ? acc0[0] : acc0[2];
        float ex1 = (g4 & 2) ? acc0[1] : acc0[3];
        float ex2 = (g4 & 2) ? acc1[0] : acc1[2];
        float ex3 = (g4 & 2) ? acc1[1] : acc1[3];
        ex0 = __shfl_xor(ex0, 32, 64);
        ex1 = __shfl_xor(ex1, 32, 64);
        ex2 = __shfl_xor(ex2, 32, 64);
        ex3 = __shfl_xor(ex3, 32, 64);

        float zi0, zi1, zf0, zf1, zc0, zc1, zo0, zo1;
        if (g4 & 2) {
            zi0 = ex0;     zi1 = ex1;     zf0 = acc0[2]; zf1 = acc0[3];
            zc0 = ex2;     zc1 = ex3;     zo0 = acc1[2]; zo1 = acc1[3];
        } else {
            zi0 = acc0[0]; zi1 = acc0[1]; zf0 = ex0;     zf1 = ex1;
            zc0 = acc1[0]; zc1 = acc1[1]; zo0 = ex2;     zo1 = ex3;
        }

        const floatx2 cold = tt ? cold1 : cold0;
        const size_t gp = tt ? gp1 : gp0;

        float ig0 = hard_sigmoid(zi0), fg0 = hard_sigmoid(zf0);
        float cg0 = fast_tanh(zc0),    og0 = hard_sigmoid(zo0);
        float cc0 = fmaf(fg0, cold[0], ig0 * cg0);
        float hh0 = og0 * fast_tanh(cc0);
        float ig1 = hard_sigmoid(zi1), fg1 = hard_sigmoid(zf1);
        float cg1 = fast_tanh(zc1),    og1 = hard_sigmoid(zo1);
        float cc1 = fmaf(fg1, cold[1], ig1 * cg1);
        float hh1 = og1 * fast_tanh(cc1);

        floatx2 cw2 = {cc0, cc1};
        *(floatx2*)(c_buf + gp * 8 + f0) = cw2;
        half2f hw = {(f16)hh0, (f16)hh1};
        *(half2f*)(h_out + gp * 8 + f0) = hw;

        o0 += 256; o1 += 256; o2 += inc2; o3 += 128;
    }
}

// Stage 1: 512 blocks (32 batches x 16 chunks); each reduces 2048 elements.
__global__ __launch_bounds__(256) void head_partial(
    const f16* __restrict__ h,       // (B, 32768) f16
    const float* __restrict__ Wout,  // (32768, 4)
    float* __restrict__ partial)     // (B*16, 4)
{
    const int b = blockIdx.x >> 4;
    const int chunk = blockIdx.x & 15;
    const int tid = threadIdx.x;
    const f16* hb = h + (size_t)b * 32768 + chunk * 2048;
    const float* wb = Wout + (size_t)(chunk * 2048) * 4;

    float acc[4] = {0.f, 0.f, 0.f, 0.f};
    #pragma unroll
    for (int it = 0; it < 8; ++it) {
        int i = it * 256 + tid;
        float hv = (float)hb[i];
        float4 wv = *(const float4*)(wb + (size_t)i * 4);
        acc[0] = fmaf(hv, wv.x, acc[0]);
        acc[1] = fmaf(hv, wv.y, acc[1]);
        acc[2] = fmaf(hv, wv.z, acc[2]);
        acc[3] = fmaf(hv, wv.w, acc[3]);
    }
    #pragma unroll
    for (int j = 0; j < 4; ++j)
        #pragma unroll
        for (int off = 32; off >= 1; off >>= 1)
            acc[j] += __shfl_down(acc[j], off, 64);

    __shared__ float red[4][4];
    int lane = tid & 63, wv2 = tid >> 6;
    if (lane == 0) {
        #pragma unroll
        for (int j = 0; j < 4; ++j) red[wv2][j] = acc[j];
    }
    __syncthreads();
    if (tid == 0) {
        #pragma unroll
        for (int j = 0; j < 4; ++j)
            partial[(size_t)blockIdx.x * 4 + j] =
                red[0][j] + red[1][j] + red[2][j] + red[3][j];
    }
}

__global__ __launch_bounds__(64) void head_finish(
    const float* __restrict__ partial,  // (B*16, 4)
    const float* __restrict__ bout,     // (4,)
    float* __restrict__ out)            // (B, 4)
{
    int b = threadIdx.x;
    if (b >= NB) return;
    float logit[4] = {bout[0], bout[1], bout[2], bout[3]};
    #pragma unroll
    for (int k = 0; k < 16; ++k) {
        const float* p = partial + (size_t)(b * 16 + k) * 4;
        logit[0] += p[0]; logit[1] += p[1]; logit[2] += p[2]; logit[3] += p[3];
    }
    float m = fmaxf(fmaxf(logit[0], logit[1]), fmaxf(logit[2], logit[3]));
    float e[4], s = 0.f;
    #pragma unroll
    for (int j = 0; j < 4; ++j) { e[j] = expf(logit[j] - m); s += e[j]; }
    float inv = 1.0f / s;
    #pragma unroll
    for (int j = 0; j < 4; ++j) out[b * 4 + j] = e[j] * inv;
}

extern "C" void kernel_launch(void* const* d_in, const int* in_sizes, int n_in,
                              void* d_out, int out_size, void* d_ws, size_t ws_size,
                              hipStream_t stream) {
    const float* x    = (const float*)d_in[0];
    const float* Wx   = (const float*)d_in[1];
    const float* Wh   = (const float*)d_in[2];
    const float* b    = (const float*)d_in[3];
    const float* Wout = (const float*)d_in[4];
    const float* bout = (const float*)d_in[5];
    float* out = (float*)d_out;

    char* ws = (char*)d_ws;
    f16*   h0      = (f16*)ws;                       // 2 MB
    f16*   h1      = (f16*)(ws + (1u << 21));        // 2 MB
    float* cb      = (float*)(ws + (1u << 22));      // 4 MB
    f16*   WB      = (f16*)(ws + (1u << 23));        // 8 KB
    float* partial = (float*)(ws + (1u << 23) + 8192);

    prepack<<<16, 256, 0, stream>>>(Wx, Wh, b, WB);

    for (int t = 0; t < NT; ++t) {
        const f16* hin = (t & 1) ? h0 : h1;   // t=0 ignores hin (first=1)
        f16* hout      = (t & 1) ? h1 : h0;
        convlstm_step<<<1024, 256, 0, stream>>>(x, WB, hin, hout, cb,
                                                t, (t == 0) ? 1 : 0);
    }
    // t = 15 wrote h1
    head_partial<<<512, 256, 0, stream>>>(h1, Wout, partial);
    head_finish<<<1, 64, 0, stream>>>(partial, bout, out);
}